// Round 9
// baseline (89.652 us; speedup 1.0000x reference)
//
#include <hip/hip_runtime.h>

#define NVOX 200000
#define TILE 256
#define WINROWS 128
#define WSHIFT 7
#define NWIN 10
#define ETG (NWIN * WINROWS)                // 1280 entry cap per 256-voxel tile (data max ~1024, R4 evidence)
#define NTILES ((NVOX + TILE - 1) / TILE)   // 782
#define NBINS (NWIN * 27)                   // 270

// ---------------- 16x16 FMA micro-kernel: acc[16] += g[16] @ W(16x16) from LDS (260-pitch rows) --
__device__ __forceinline__ void fma16x16(const float4* __restrict__ wrow,
                                         float4 f0, float4 f1, float4 f2, float4 f3,
                                         float acc[16]) {
    const float g[16] = {f0.x, f0.y, f0.z, f0.w, f1.x, f1.y, f1.z, f1.w,
                         f2.x, f2.y, f2.z, f2.w, f3.x, f3.y, f3.z, f3.w};
    #pragma unroll
    for (int cc = 0; cc < 16; ++cc) {
        float gc = g[cc];
        float4 w0 = wrow[cc * 4 + 0];
        float4 w1 = wrow[cc * 4 + 1];
        float4 w2 = wrow[cc * 4 + 2];
        float4 w3 = wrow[cc * 4 + 3];
        acc[0]  += gc * w0.x; acc[1]  += gc * w0.y; acc[2]  += gc * w0.z; acc[3]  += gc * w0.w;
        acc[4]  += gc * w1.x; acc[5]  += gc * w1.y; acc[6]  += gc * w1.z; acc[7]  += gc * w1.w;
        acc[8]  += gc * w2.x; acc[9]  += gc * w2.y; acc[10] += gc * w2.z; acc[11] += gc * w2.w;
        acc[12] += gc * w3.x; acc[13] += gc * w3.y; acc[14] += gc * w3.z; acc[15] += gc * w3.w;
    }
}

// ---------------- K1: compact + (window,k)-binned entry list + rowstart + conv0 ----------------
__global__ __launch_bounds__(256) void k1_compact_conv0(
    const float* __restrict__ feats,  // [N,4]
    const int* __restrict__ nbr,      // [N,27]
    const float* __restrict__ W,      // [27,4,16]
    const float* __restrict__ s, const float* __restrict__ b,
    int* __restrict__ gEnt,           // [NTILES,ETG]  (idx<<5)|k, sorted by (window,k)
    unsigned short* __restrict__ gVm, // [NTILES,ETG]  voxel-major row position
    int* __restrict__ rowstartG,      // [NTILES,TILE+1]
    int* __restrict__ wbaseG,         // [NTILES,NWIN+1] entry-range per window
    float* __restrict__ x) {          // [N,16]
    __shared__ int   lnbr[TILE * 27];             // 27648 B
    __shared__ __align__(16) float Wl[27 * 68];   //  7344 B
    __shared__ int   bhist[NBINS];                //  1080 B
    __shared__ int   bbase[NBINS];                //  1080 B
    __shared__ int   rs[TILE];                    //  1024 B
    __shared__ int   eloc[ETG];                   //  5120 B
    __shared__ unsigned short evm[ETG];           //  2560 B
    int t = threadIdx.x;
    int tile = blockIdx.x;
    int base = tile * TILE;
    for (int i = t; i < 27 * 64; i += 256)
        Wl[(i >> 6) * 68 + (i & 63)] = W[i];
    for (int i = t; i < NBINS; i += 256) bhist[i] = 0;
    int nv = NVOX - base; if (nv > TILE) nv = TILE;
    const int* gsrc = nbr + base * 27;
    for (int i = t; i < nv * 27; i += 256)
        lnbr[i] = gsrc[i];            // fully coalesced
    __syncthreads();

    // pass 1: in-place compaction
    int c = 0;
    int* row = lnbr + t * 27;
    if (t < nv) {
        #pragma unroll
        for (int k = 0; k < 27; ++k) {
            int idx = row[k];
            if (idx >= 0) { row[c] = (idx << 5) | k; ++c; }
        }
    }
    // inclusive scan of c (Hillis-Steele, 256)
    rs[t] = c;
    __syncthreads();
    #pragma unroll
    for (int off = 1; off < TILE; off <<= 1) {
        int v = rs[t];
        if (t >= off) v += rs[t - off];
        __syncthreads();
        rs[t] = v;
        __syncthreads();
    }
    int excl = rs[t] - c;
    int total = rs[TILE - 1];
    int tot = total < ETG ? total : ETG;
    rowstartG[tile * (TILE + 1) + t] = excl < tot ? excl : tot;
    if (t == TILE - 1) rowstartG[tile * (TILE + 1) + TILE] = tot;

    // pass 2: histogram by (window, k)
    for (int j = 0; j < c; ++j) {
        int vm = excl + j;
        if (vm < ETG) {
            int k = row[j] & 31;
            atomicAdd(&bhist[(vm >> WSHIFT) * 27 + k], 1);
        }
    }
    __syncthreads();
    if (t == 0) {
        int a = 0;
        for (int i = 0; i < NBINS; ++i) { bbase[i] = a; a += bhist[i]; }
        for (int w = 0; w < NWIN; ++w)
            wbaseG[tile * (NWIN + 1) + w] = bbase[w * 27];
        wbaseG[tile * (NWIN + 1) + NWIN] = a;   // == tot
    }
    __syncthreads();
    for (int i = t; i < NBINS; i += 256) bhist[i] = 0;  // reuse as cursor
    __syncthreads();
    // pass 3: scatter into (window,k)-sorted list
    for (int j = 0; j < c; ++j) {
        int vm = excl + j;
        if (vm < ETG) {
            int e = row[j];
            int bin = (vm >> WSHIFT) * 27 + (e & 31);
            int pos = bbase[bin] + atomicAdd(&bhist[bin], 1);
            eloc[pos] = e;
            evm[pos] = (unsigned short)vm;
        }
    }
    __syncthreads();
    for (int i = t; i < tot; i += 256) {
        gEnt[tile * ETG + i] = eloc[i];
        gVm[tile * ETG + i]  = evm[i];
    }

    // conv0: uniform loop over this thread's compacted entries (from LDS)
    if (t >= nv) return;
    float acc[16];
    #pragma unroll
    for (int d = 0; d < 16; ++d) acc[d] = 0.f;
    int e = row[0];                   // c >= 1 (center k=13 always present)
    float4 f = *(const float4*)(feats + (e >> 5) * 4);
    int j = 0;
    while (true) {
        bool more = (++j < c);
        int en = e; float4 fn = f;
        if (more) {
            en = row[j];
            fn = *(const float4*)(feats + (en >> 5) * 4);
        }
        {
            const float4* wrow = (const float4*)(Wl + (e & 31) * 68);
            float g[4] = {f.x, f.y, f.z, f.w};
            #pragma unroll
            for (int cc = 0; cc < 4; ++cc) {
                float gc = g[cc];
                float4 w0 = wrow[cc * 4 + 0];
                float4 w1 = wrow[cc * 4 + 1];
                float4 w2 = wrow[cc * 4 + 2];
                float4 w3 = wrow[cc * 4 + 3];
                acc[0]  += gc * w0.x; acc[1]  += gc * w0.y; acc[2]  += gc * w0.z; acc[3]  += gc * w0.w;
                acc[4]  += gc * w1.x; acc[5]  += gc * w1.y; acc[6]  += gc * w1.z; acc[7]  += gc * w1.w;
                acc[8]  += gc * w2.x; acc[9]  += gc * w2.y; acc[10] += gc * w2.z; acc[11] += gc * w2.w;
                acc[12] += gc * w3.x; acc[13] += gc * w3.y; acc[14] += gc * w3.z; acc[15] += gc * w3.w;
            }
        }
        if (!more) break;
        e = en; f = fn;
    }
    int n = base + t;
    float4* o = (float4*)(x + n * 16);
    #pragma unroll
    for (int q = 0; q < 4; ++q) {
        float4 r;
        float v0 = acc[q * 4 + 0] * s[q * 4 + 0] + b[q * 4 + 0];
        float v1 = acc[q * 4 + 1] * s[q * 4 + 1] + b[q * 4 + 1];
        float v2 = acc[q * 4 + 2] * s[q * 4 + 2] + b[q * 4 + 2];
        float v3 = acc[q * 4 + 3] * s[q * 4 + 3] + b[q * 4 + 3];
        r.x = v0 > 0.f ? v0 : 0.f;
        r.y = v1 > 0.f ? v1 : 0.f;
        r.z = v2 > 0.f ? v2 : 0.f;
        r.w = v3 > 0.f ? v3 : 0.f;
        o[q] = r;
    }
}

// ---------------- shared conv body: windowed, cross-window prefetched, wave-rotated ------------
__device__ __forceinline__ void conv16_windowed(const float* __restrict__ fin,
                                                const int* __restrict__ gE,
                                                const unsigned short* __restrict__ gV,
                                                const int* __restrict__ wb,
                                                const float* __restrict__ Wl,  // LDS, 260-pitch
                                                float* __restrict__ partial,   // LDS, 20-pitch
                                                int rstart, int rend, int t,
                                                float acc[16]) {
    #pragma unroll
    for (int d = 0; d < 16; ++d) acc[d] = 0.f;
    // prologue: load window 0's entry for this thread (rotation(0) == t)
    bool act = false;
    int e = 0, vm = 0;
    float4 f0, f1, f2, f3;
    {
        int i0 = wb[0] + t;
        act = (t < WINROWS) && (i0 < wb[1]);
        if (act) {
            e = gE[i0];
            vm = gV[i0];
            const float4* fp = (const float4*)(fin + (e >> 5) * 16);
            f0 = fp[0]; f1 = fp[1]; f2 = fp[2]; f3 = fp[3];
        }
    }
    for (int w = 0; w < NWIN; ++w) {
        int lo = w * WINROWS;
        // issue next window's entry + feature gather BEFORE computing current (latency hides
        // under this window's FMA block + phase-2 drain)
        bool act2 = false;
        int e2 = 0, vm2 = 0;
        float4 g0, g1, g2, g3;
        if (w + 1 < NWIN) {
            int rt = (t + (((w + 1) & 3) << 6)) & 255;   // rotate active lanes across the 4 waves
            int i2 = wb[w + 1] + rt;
            act2 = (rt < WINROWS) && (i2 < wb[w + 2]);
            if (act2) {
                e2 = gE[i2];
                vm2 = gV[i2];
                const float4* fq = (const float4*)(fin + (e2 >> 5) * 16);
                g0 = fq[0]; g1 = fq[1]; g2 = fq[2]; g3 = fq[3];
            }
        }
        // phase 1: compute current window's partial row (k near-uniform -> broadcast W reads)
        if (act) {
            float pa[16];
            #pragma unroll
            for (int d = 0; d < 16; ++d) pa[d] = 0.f;
            fma16x16((const float4*)(Wl + (e & 31) * 260), f0, f1, f2, f3, pa);
            float4* pr = (float4*)(partial + (vm - lo) * 20);  // pitch 20 -> 8 bank-start spread
            #pragma unroll
            for (int q = 0; q < 4; ++q) {
                float4 r;
                r.x = pa[q * 4 + 0]; r.y = pa[q * 4 + 1];
                r.z = pa[q * 4 + 2]; r.w = pa[q * 4 + 3];
                pr[q] = r;
            }
        }
        __syncthreads();
        // phase 2: drain this window's rows into per-voxel accumulators
        int a  = rstart > lo ? rstart : lo;
        int bd = rend < lo + WINROWS ? rend : lo + WINROWS;
        for (int r = a; r < bd; ++r) {
            const float4* pr = (const float4*)(partial + (r - lo) * 20);
            #pragma unroll
            for (int q = 0; q < 4; ++q) {
                float4 v = pr[q];
                acc[q * 4 + 0] += v.x; acc[q * 4 + 1] += v.y;
                acc[q * 4 + 2] += v.z; acc[q * 4 + 3] += v.w;
            }
        }
        __syncthreads();
        act = act2; e = e2; vm = vm2;
        f0 = g0; f1 = g1; f2 = g2; f3 = g3;
    }
}

// ---------------- K2: conv1 (16->16), relu(conv*s+b) ----------------
__global__ __launch_bounds__(256, 4) void k2_conv1(
    const float* __restrict__ fin,    // x [N,16]
    const int* __restrict__ gEnt, const unsigned short* __restrict__ gVm,
    const int* __restrict__ rowstartG, const int* __restrict__ wbaseG,
    const float* __restrict__ W,      // [27,16,16]
    const float* __restrict__ s, const float* __restrict__ b,
    float* __restrict__ out) {        // h [N,16]
    __shared__ __align__(16) float Wl[27 * 260];          // 28080 B
    __shared__ __align__(16) float partial[WINROWS * 20]; // 10240 B
    __shared__ int rs[TILE + 1];
    __shared__ int wb[NWIN + 1];
    int t = threadIdx.x;
    int tile = blockIdx.x;
    for (int i = t; i < 27 * 256; i += 256)
        Wl[(i >> 8) * 260 + (i & 255)] = W[i];
    rs[t] = rowstartG[tile * (TILE + 1) + t];
    if (t == 0) rs[TILE] = rowstartG[tile * (TILE + 1) + TILE];
    if (t < NWIN + 1) wb[t] = wbaseG[tile * (NWIN + 1) + t];
    __syncthreads();
    int rstart = rs[t];
    int rend = rs[t + 1];
    float acc[16];
    conv16_windowed(fin, gEnt + tile * ETG, gVm + tile * ETG, wb, Wl, partial,
                    rstart, rend, t, acc);
    int n = tile * TILE + t;
    if (n >= NVOX) return;
    float4* o = (float4*)(out + n * 16);
    #pragma unroll
    for (int q = 0; q < 4; ++q) {
        float4 r;
        float v0 = acc[q * 4 + 0] * s[q * 4 + 0] + b[q * 4 + 0];
        float v1 = acc[q * 4 + 1] * s[q * 4 + 1] + b[q * 4 + 1];
        float v2 = acc[q * 4 + 2] * s[q * 4 + 2] + b[q * 4 + 2];
        float v3 = acc[q * 4 + 3] * s[q * 4 + 3] + b[q * 4 + 3];
        r.x = v0 > 0.f ? v0 : 0.f;
        r.y = v1 > 0.f ? v1 : 0.f;
        r.z = v2 > 0.f ? v2 : 0.f;
        r.w = v3 > 0.f ? v3 : 0.f;
        o[q] = r;
    }
}

// ---------------- K3: conv2 + residual + relu + final 16->3 linear ----------------
__global__ __launch_bounds__(256, 4) void k3_conv2_final(
    const float* __restrict__ fin,    // h [N,16]
    const int* __restrict__ gEnt, const unsigned short* __restrict__ gVm,
    const int* __restrict__ rowstartG, const int* __restrict__ wbaseG,
    const float* __restrict__ W,      // [27,16,16]
    const float* __restrict__ s, const float* __restrict__ b,
    const float* __restrict__ idn,    // x [N,16]
    const float* __restrict__ Wlin,   // [16,3]
    const float* __restrict__ blin,   // [3]
    float* __restrict__ out) {        // [N,3]
    __shared__ __align__(16) float Wl[27 * 260];
    __shared__ __align__(16) float partial[WINROWS * 20];
    __shared__ int rs[TILE + 1];
    __shared__ int wb[NWIN + 1];
    int t = threadIdx.x;
    int tile = blockIdx.x;
    for (int i = t; i < 27 * 256; i += 256)
        Wl[(i >> 8) * 260 + (i & 255)] = W[i];
    rs[t] = rowstartG[tile * (TILE + 1) + t];
    if (t == 0) rs[TILE] = rowstartG[tile * (TILE + 1) + TILE];
    if (t < NWIN + 1) wb[t] = wbaseG[tile * (NWIN + 1) + t];
    __syncthreads();
    int rstart = rs[t];
    int rend = rs[t + 1];
    float acc[16];
    conv16_windowed(fin, gEnt + tile * ETG, gVm + tile * ETG, wb, Wl, partial,
                    rstart, rend, t, acc);
    int n = tile * TILE + t;
    if (n >= NVOX) return;
    const float4* ip = (const float4*)(idn + n * 16);
    float4 i0 = ip[0], i1 = ip[1], i2 = ip[2], i3 = ip[3];
    float id[16] = {i0.x, i0.y, i0.z, i0.w, i1.x, i1.y, i1.z, i1.w,
                    i2.x, i2.y, i2.z, i2.w, i3.x, i3.y, i3.z, i3.w};
    float o0 = blin[0], o1 = blin[1], o2 = blin[2];
    #pragma unroll
    for (int d = 0; d < 16; ++d) {
        float v = acc[d] * s[d] + b[d] + id[d];
        v = v > 0.f ? v : 0.f;
        o0 += v * Wlin[d * 3 + 0];
        o1 += v * Wlin[d * 3 + 1];
        o2 += v * Wlin[d * 3 + 2];
    }
    out[n * 3 + 0] = o0;
    out[n * 3 + 1] = o1;
    out[n * 3 + 2] = o2;
}

extern "C" void kernel_launch(void* const* d_in, const int* in_sizes, int n_in,
                              void* d_out, int out_size, void* d_ws, size_t ws_size,
                              hipStream_t stream) {
    const float* feats = (const float*)d_in[0];
    const int*   nbr   = (const int*)d_in[1];
    const float* W0    = (const float*)d_in[2];
    const float* s0    = (const float*)d_in[3];
    const float* b0    = (const float*)d_in[4];
    const float* W1    = (const float*)d_in[5];
    const float* s1    = (const float*)d_in[6];
    const float* b1    = (const float*)d_in[7];
    const float* W2    = (const float*)d_in[8];
    const float* s2    = (const float*)d_in[9];
    const float* b2    = (const float*)d_in[10];
    const float* Wlin  = (const float*)d_in[11];
    const float* blin  = (const float*)d_in[12];
    float* out = (float*)d_out;

    char* ws = (char*)d_ws;
    int*            gEnt      = (int*)(ws);                        // 782*1280*4 = 4,003,840
    unsigned short* gVm       = (unsigned short*)(ws + 4003840);   // 782*1280*2 = 2,001,920
    int*            rowstartG = (int*)(ws + 6005760);              // 782*257*4  =   803,896
    int*            wbaseG    = (int*)(ws + 6809664);              // 782*11*4   =    34,408
    float*          x         = (float*)(ws + 6844096);            // 12,800,000
    float*          h         = (float*)(ws + 19644096);           // 12,800,000

    k1_compact_conv0<<<NTILES, TILE, 0, stream>>>(feats, nbr, W0, s0, b0,
                                                  gEnt, gVm, rowstartG, wbaseG, x);
    k2_conv1<<<NTILES, TILE, 0, stream>>>(x, gEnt, gVm, rowstartG, wbaseG, W1, s1, b1, h);
    k3_conv2_final<<<NTILES, TILE, 0, stream>>>(h, gEnt, gVm, rowstartG, wbaseG, W2, s2, b2,
                                                x, Wlin, blin, out);
}

// Round 10
// 76.940 us; speedup vs baseline: 1.1652x; 1.1652x over previous
//
#include <hip/hip_runtime.h>
#include <cstdint>

#define NVOX 200000
#define T1 128
#define NT1 ((NVOX + T1 - 1) / T1)      // 1563
#define VPB 64
#define NT2 ((NVOX + VPB - 1) / VPB)    // 3125
#define WPITCH 132                       // uints per k-row of packed W (528 B -> k*4 mod 32 bank spread)

typedef _Float16 h2 __attribute__((ext_vector_type(2)));

__device__ __forceinline__ uint32_t packh2(float a, float b) {
    h2 v; v.x = (_Float16)a; v.y = (_Float16)b;
    return __builtin_bit_cast(uint32_t, v);
}
__device__ __forceinline__ h2 toh2(uint32_t u) { return __builtin_bit_cast(h2, u); }

// ---------------- K0: pre-pack W1,W2 into dot2 layout wp[k*128 + d*8 + p] = (W[k][2p][d],W[k][2p+1][d])
__global__ __launch_bounds__(256) void k0_pack(const float* __restrict__ W1,
                                               const float* __restrict__ W2,
                                               uint32_t* __restrict__ wp1,
                                               uint32_t* __restrict__ wp2) {
    int i = blockIdx.x * 256 + threadIdx.x;
    if (i >= 2 * 3456) return;
    int half = i >= 3456;
    int r = i - half * 3456;
    const float* W = half ? W2 : W1;
    uint32_t* wp = half ? wp2 : wp1;
    int k = r >> 7, j = r & 127, d = j >> 3, p = j & 7;
    float a = W[(k * 16 + 2 * p) * 16 + d];
    float b = W[(k * 16 + 2 * p + 1) * 16 + d];
    wp[r] = packh2(a, b);
}

// ---------------- K1: coalesced compact (LDS-staged nbr) + conv0 (C=4 -> D=16), x out f16 -------
__global__ __launch_bounds__(128) void k1_compact_conv0(
    const float* __restrict__ feats,  // [N,4] fp32
    const int* __restrict__ nbr,      // [N,27]
    const float* __restrict__ W,      // [27,4,16]
    const float* __restrict__ s, const float* __restrict__ b,
    int* __restrict__ ent,            // [27,N] packed (idx<<5)|k, column-major slices
    int* __restrict__ cnt,            // [N]
    uint32_t* __restrict__ xh) {      // [N,8] packed f16 pairs
    __shared__ int   lnbr[T1 * 27];               // 13824 B
    __shared__ __align__(16) float Wl[27 * 68];   //  7344 B
    int t = threadIdx.x;
    int base = blockIdx.x * T1;
    for (int i = t; i < 27 * 64; i += T1)
        Wl[(i >> 6) * 68 + (i & 63)] = W[i];
    int nv = NVOX - base; if (nv > T1) nv = T1;
    const int* gsrc = nbr + base * 27;
    for (int i = t; i < nv * 27; i += T1)
        lnbr[i] = gsrc[i];            // fully coalesced
    __syncthreads();

    int n = base + t;
    if (t >= nv) return;
    int* row = lnbr + t * 27;
    int c = 0;
    #pragma unroll
    for (int k = 0; k < 27; ++k) {
        int idx = row[k];
        if (idx >= 0) {
            int e = (idx << 5) | k;
            row[c] = e;               // in-place compaction (c <= k)
            ent[c * NVOX + n] = e;
            ++c;
        }
    }
    cnt[n] = c;

    // conv0: uniform loop over compacted entries (LDS), 1-deep prefetched feature gathers
    float acc[16];
    #pragma unroll
    for (int d = 0; d < 16; ++d) acc[d] = 0.f;
    int e = row[0];                   // c >= 1 (center k=13 always present)
    float4 f = *(const float4*)(feats + (e >> 5) * 4);
    int j = 0;
    while (true) {
        bool more = (++j < c);
        int en = e; float4 fn = f;
        if (more) {
            en = row[j];
            fn = *(const float4*)(feats + (en >> 5) * 4);
        }
        {
            const float4* wrow = (const float4*)(Wl + (e & 31) * 68);
            float g[4] = {f.x, f.y, f.z, f.w};
            #pragma unroll
            for (int cc = 0; cc < 4; ++cc) {
                float gc = g[cc];
                float4 w0 = wrow[cc * 4 + 0];
                float4 w1 = wrow[cc * 4 + 1];
                float4 w2 = wrow[cc * 4 + 2];
                float4 w3 = wrow[cc * 4 + 3];
                acc[0]  += gc * w0.x; acc[1]  += gc * w0.y; acc[2]  += gc * w0.z; acc[3]  += gc * w0.w;
                acc[4]  += gc * w1.x; acc[5]  += gc * w1.y; acc[6]  += gc * w1.z; acc[7]  += gc * w1.w;
                acc[8]  += gc * w2.x; acc[9]  += gc * w2.y; acc[10] += gc * w2.z; acc[11] += gc * w2.w;
                acc[12] += gc * w3.x; acc[13] += gc * w3.y; acc[14] += gc * w3.z; acc[15] += gc * w3.w;
            }
        }
        if (!more) break;
        e = en; f = fn;
    }
    float v[16];
    #pragma unroll
    for (int d = 0; d < 16; ++d) {
        float u = acc[d] * s[d] + b[d];
        v[d] = u > 0.f ? u : 0.f;
    }
    uint4 u0, u1;
    u0.x = packh2(v[0], v[1]);  u0.y = packh2(v[2], v[3]);
    u0.z = packh2(v[4], v[5]);  u0.w = packh2(v[6], v[7]);
    u1.x = packh2(v[8], v[9]);  u1.y = packh2(v[10], v[11]);
    u1.z = packh2(v[12], v[13]); u1.w = packh2(v[14], v[15]);
    ((uint4*)xh)[n * 2 + 0] = u0;
    ((uint4*)xh)[n * 2 + 1] = u1;
}

// ---------------- shared f16-dot2 conv core: 4 threads/voxel, returns acc[4] for d0..d0+3 -------
__device__ __forceinline__ void conv16_dot2(const uint32_t* __restrict__ fin,  // [N,8] f16 pairs
                                            const int* __restrict__ ent,
                                            int c, int n, int d0,
                                            const uint32_t* __restrict__ wl,   // LDS [27][WPITCH]
                                            float acc[4]) {
    #pragma unroll
    for (int d = 0; d < 4; ++d) acc[d] = 0.f;
    if (c <= 0) return;
    int e = ent[n];
    const uint4* fp = (const uint4*)(fin + (e >> 5) * 8);
    uint4 fa = fp[0], fb = fp[1];
    int j = 0;
    while (true) {
        bool more = (++j < c);
        int en = e;
        uint4 ga = fa, gb = fb;
        if (more) {
            en = ent[j * NVOX + n];   // prefetch next entry + feature row (32 B)
            const uint4* fq = (const uint4*)(fin + (en >> 5) * 8);
            ga = fq[0]; gb = fq[1];
        }
        {
            int k = e & 31;
            h2 f0 = toh2(fa.x), f1 = toh2(fa.y), f2 = toh2(fa.z), f3 = toh2(fa.w);
            h2 f4 = toh2(fb.x), f5 = toh2(fb.y), f6 = toh2(fb.z), f7 = toh2(fb.w);
            const uint32_t* wk = wl + k * WPITCH + d0 * 8;
            #pragma unroll
            for (int dd = 0; dd < 4; ++dd) {
                uint4 wa = *(const uint4*)(wk + dd * 8);
                uint4 wb = *(const uint4*)(wk + dd * 8 + 4);
                float a = acc[dd];
                a = __builtin_amdgcn_fdot2(f0, toh2(wa.x), a, false);
                a = __builtin_amdgcn_fdot2(f1, toh2(wa.y), a, false);
                a = __builtin_amdgcn_fdot2(f2, toh2(wa.z), a, false);
                a = __builtin_amdgcn_fdot2(f3, toh2(wa.w), a, false);
                a = __builtin_amdgcn_fdot2(f4, toh2(wb.x), a, false);
                a = __builtin_amdgcn_fdot2(f5, toh2(wb.y), a, false);
                a = __builtin_amdgcn_fdot2(f6, toh2(wb.z), a, false);
                a = __builtin_amdgcn_fdot2(f7, toh2(wb.w), a, false);
                acc[dd] = a;
            }
        }
        if (!more) break;
        e = en; fa = ga; fb = gb;
    }
}

// ---------------- per-block prologue: stage packed W + rank 64 voxels by cnt --------------------
__device__ __forceinline__ void stage_and_rank(const uint32_t* __restrict__ wp,
                                               const int* __restrict__ cnt,
                                               uint32_t* __restrict__ wl,
                                               int* __restrict__ lcnt, int* __restrict__ lperm,
                                               int base, int t) {
    for (int i = t; i < 3456; i += 256)
        wl[(i >> 7) * WPITCH + (i & 127)] = wp[i];   // coalesced (pre-packed by k0)
    if (t < VPB) {
        int n = base + t;
        lcnt[t] = (n < NVOX) ? cnt[n] : 0;
    }
    __syncthreads();
    if (t < VPB) {
        int me = lcnt[t];
        int r = 0;
        #pragma unroll 8
        for (int j2 = 0; j2 < VPB; ++j2) {
            int oj = lcnt[j2];
            r += (oj < me) || (oj == me && j2 < t);
        }
        lperm[r] = t;                 // ascending cnt -> waves get uniform trip counts
    }
    __syncthreads();
}

// ---------------- K2: conv1 (16->16) f16 dot2, relu(conv*s+b), h out f16 ------------------------
__global__ __launch_bounds__(256, 6) void k2_conv1(
    const uint32_t* __restrict__ xh,  // [N,8] f16 pairs
    const int* __restrict__ ent, const int* __restrict__ cnt,
    const uint32_t* __restrict__ wp,  // packed W1
    const float* __restrict__ s, const float* __restrict__ b,
    uint32_t* __restrict__ hh) {      // [N,8] f16 pairs
    __shared__ __align__(16) uint32_t wl[27 * WPITCH];  // 14256 B
    __shared__ int lcnt[VPB];
    __shared__ int lperm[VPB];
    int t = threadIdx.x;
    int base = blockIdx.x * VPB;
    stage_and_rank(wp, cnt, wl, lcnt, lperm, base, t);
    int g = t >> 2, cg = t & 3;
    int lv = lperm[g];
    int n = base + lv;
    bool valid = n < NVOX;
    int c = lcnt[lv];
    int d0 = cg * 4;
    float acc[4];
    conv16_dot2(xh, ent, valid ? c : 0, n, d0, wl, acc);
    if (!valid) return;
    float v[4];
    #pragma unroll
    for (int dd = 0; dd < 4; ++dd) {
        float u = acc[dd] * s[d0 + dd] + b[d0 + dd];
        v[dd] = u > 0.f ? u : 0.f;
    }
    uint2 o;
    o.x = packh2(v[0], v[1]);
    o.y = packh2(v[2], v[3]);
    *(uint2*)(hh + n * 8 + cg * 2) = o;
}

// ---------------- K3: conv2 f16 dot2 + residual + relu + final 16->3 linear ---------------------
__global__ __launch_bounds__(256, 6) void k3_conv2_final(
    const uint32_t* __restrict__ hh,  // [N,8]
    const int* __restrict__ ent, const int* __restrict__ cnt,
    const uint32_t* __restrict__ wp,  // packed W2
    const float* __restrict__ s, const float* __restrict__ b,
    const uint32_t* __restrict__ xh,  // residual [N,8]
    const float* __restrict__ Wlin,   // [16,3]
    const float* __restrict__ blin,   // [3]
    float* __restrict__ out) {        // [N,3] fp32
    __shared__ __align__(16) uint32_t wl[27 * WPITCH];
    __shared__ int lcnt[VPB];
    __shared__ int lperm[VPB];
    int t = threadIdx.x;
    int base = blockIdx.x * VPB;
    stage_and_rank(wp, cnt, wl, lcnt, lperm, base, t);
    int g = t >> 2, cg = t & 3;
    int lv = lperm[g];
    int n = base + lv;
    bool valid = n < NVOX;
    int c = lcnt[lv];
    int d0 = cg * 4;
    float acc[4];
    conv16_dot2(hh, ent, valid ? c : 0, n, d0, wl, acc);
    float o0 = 0.f, o1 = 0.f, o2 = 0.f;
    if (valid) {
        uint2 iv = *(const uint2*)(xh + n * 8 + cg * 2);
        h2 i0 = toh2(iv.x), i1 = toh2(iv.y);
        float idn[4] = {(float)i0.x, (float)i0.y, (float)i1.x, (float)i1.y};
        #pragma unroll
        for (int dd = 0; dd < 4; ++dd) {
            int d = d0 + dd;
            float u = acc[dd] * s[d] + b[d] + idn[dd];
            u = u > 0.f ? u : 0.f;
            o0 += u * Wlin[d * 3 + 0];
            o1 += u * Wlin[d * 3 + 1];
            o2 += u * Wlin[d * 3 + 2];
        }
    }
    // reduce across the 4 lanes of this voxel (lanes g*4 .. g*4+3)
    o0 += __shfl_xor(o0, 1); o0 += __shfl_xor(o0, 2);
    o1 += __shfl_xor(o1, 1); o1 += __shfl_xor(o1, 2);
    o2 += __shfl_xor(o2, 1); o2 += __shfl_xor(o2, 2);
    if (valid && cg == 0) {
        out[n * 3 + 0] = o0 + blin[0];
        out[n * 3 + 1] = o1 + blin[1];
        out[n * 3 + 2] = o2 + blin[2];
    }
}

extern "C" void kernel_launch(void* const* d_in, const int* in_sizes, int n_in,
                              void* d_out, int out_size, void* d_ws, size_t ws_size,
                              hipStream_t stream) {
    const float* feats = (const float*)d_in[0];
    const int*   nbr   = (const int*)d_in[1];
    const float* W0    = (const float*)d_in[2];
    const float* s0    = (const float*)d_in[3];
    const float* b0    = (const float*)d_in[4];
    const float* W1    = (const float*)d_in[5];
    const float* s1    = (const float*)d_in[6];
    const float* b1    = (const float*)d_in[7];
    const float* W2    = (const float*)d_in[8];
    const float* s2    = (const float*)d_in[9];
    const float* b2    = (const float*)d_in[10];
    const float* Wlin  = (const float*)d_in[11];
    const float* blin  = (const float*)d_in[12];
    float* out = (float*)d_out;

    char* ws = (char*)d_ws;
    int*      ent = (int*)(ws);                    // 27*N*4 = 21,600,000
    int*      cnt = (int*)(ws + 21600000);         //    800,000
    uint32_t* xh  = (uint32_t*)(ws + 22400000);    //  6,400,000
    uint32_t* hh  = (uint32_t*)(ws + 28800000);    //  6,400,000
    uint32_t* wp1 = (uint32_t*)(ws + 35200000);    //     13,824
    uint32_t* wp2 = (uint32_t*)(ws + 35213824);    //     13,824

    k0_pack<<<27, 256, 0, stream>>>(W1, W2, wp1, wp2);
    k1_compact_conv0<<<NT1, T1, 0, stream>>>(feats, nbr, W0, s0, b0, ent, cnt, xh);
    k2_conv1<<<NT2, 256, 0, stream>>>(xh, ent, cnt, wp1, s1, b1, hh);
    k3_conv2_final<<<NT2, 256, 0, stream>>>(hh, ent, cnt, wp2, s2, b2, xh, Wlin, blin, out);
}

// Round 11
// 76.011 us; speedup vs baseline: 1.1795x; 1.0122x over previous
//
#include <hip/hip_runtime.h>
#include <cstdint>

#define NVOX 200000
#define T1 128
#define NT1 ((NVOX + T1 - 1) / T1)      // 1563
#define VPB 64
#define NT2 ((NVOX + VPB - 1) / VPB)    // 3125
#define WPITCH 132                       // uints per k-row of packed W (528 B)

typedef _Float16 h2 __attribute__((ext_vector_type(2)));

__device__ __forceinline__ uint32_t packh2(float a, float b) {
    h2 v; v.x = (_Float16)a; v.y = (_Float16)b;
    return __builtin_bit_cast(uint32_t, v);
}
__device__ __forceinline__ h2 toh2(uint32_t u) { return __builtin_bit_cast(h2, u); }

// ---------------- K0: pre-pack W1,W2 into dot2 layout wp[k*128 + d*8 + p] = (W[k][2p][d],W[k][2p+1][d])
__global__ __launch_bounds__(256) void k0_pack(const float* __restrict__ W1,
                                               const float* __restrict__ W2,
                                               uint32_t* __restrict__ wp1,
                                               uint32_t* __restrict__ wp2) {
    int i = blockIdx.x * 256 + threadIdx.x;
    if (i >= 2 * 3456) return;
    int half = i >= 3456;
    int r = i - half * 3456;
    const float* W = half ? W2 : W1;
    uint32_t* wp = half ? wp2 : wp1;
    int k = r >> 7, j = r & 127, d = j >> 3, p = j & 7;
    float a = W[(k * 16 + 2 * p) * 16 + d];
    float b = W[(k * 16 + 2 * p + 1) * 16 + d];
    wp[r] = packh2(a, b);
}

// ---------------- conv0 4-channel-block FMA for one entry ----------------
__device__ __forceinline__ void conv0_entry(int e, float4 f, const float* __restrict__ Wl,
                                            float acc[16]) {
    const float4* wrow = (const float4*)(Wl + (e & 31) * 68);
    float g[4] = {f.x, f.y, f.z, f.w};
    #pragma unroll
    for (int cc = 0; cc < 4; ++cc) {
        float gc = g[cc];
        float4 w0 = wrow[cc * 4 + 0];
        float4 w1 = wrow[cc * 4 + 1];
        float4 w2 = wrow[cc * 4 + 2];
        float4 w3 = wrow[cc * 4 + 3];
        acc[0]  += gc * w0.x; acc[1]  += gc * w0.y; acc[2]  += gc * w0.z; acc[3]  += gc * w0.w;
        acc[4]  += gc * w1.x; acc[5]  += gc * w1.y; acc[6]  += gc * w1.z; acc[7]  += gc * w1.w;
        acc[8]  += gc * w2.x; acc[9]  += gc * w2.y; acc[10] += gc * w2.z; acc[11] += gc * w2.w;
        acc[12] += gc * w3.x; acc[13] += gc * w3.y; acc[14] += gc * w3.z; acc[15] += gc * w3.w;
    }
}

// ---------------- K1: coalesced compact + cnt-rank + conv0 (batch-4 gathers), x out f16 ---------
__global__ __launch_bounds__(128) void k1_compact_conv0(
    const float* __restrict__ feats,  // [N,4] fp32
    const int* __restrict__ nbr,      // [N,27]
    const float* __restrict__ W,      // [27,4,16]
    const float* __restrict__ s, const float* __restrict__ b,
    int* __restrict__ ent,            // [27,N] packed (idx<<5)|k, column-major slices
    int* __restrict__ cnt,            // [N]
    uint32_t* __restrict__ xh) {      // [N,8] packed f16 pairs
    __shared__ int   lnbr[T1 * 27];               // 13824 B
    __shared__ __align__(16) float Wl[27 * 68];   //  7344 B
    __shared__ int   lcnt[T1];
    __shared__ int   lperm[T1];
    int t = threadIdx.x;
    int base = blockIdx.x * T1;
    for (int i = t; i < 27 * 64; i += T1)
        Wl[(i >> 6) * 68 + (i & 63)] = W[i];
    int nv = NVOX - base; if (nv > T1) nv = T1;
    const int* gsrc = nbr + base * 27;
    for (int i = t; i < nv * 27; i += T1)
        lnbr[i] = gsrc[i];            // fully coalesced
    __syncthreads();

    int c = 0;
    {
        int* row = lnbr + t * 27;
        if (t < nv) {
            #pragma unroll
            for (int k = 0; k < 27; ++k) {
                int idx = row[k];
                if (idx >= 0) {
                    int e = (idx << 5) | k;
                    row[c] = e;               // in-place compaction (c <= k)
                    ent[c * NVOX + (base + t)] = e;
                    ++c;
                }
            }
            cnt[base + t] = c;
        }
    }
    lcnt[t] = c;                      // 0 for invalid -> ranked first, no work
    __syncthreads();
    {
        int me = lcnt[t];
        int r = 0;
        for (int j2 = 0; j2 < T1; ++j2) {
            int oj = lcnt[j2];
            r += (oj < me) || (oj == me && j2 < t);
        }
        lperm[r] = t;                 // ascending cnt -> uniform wave trip counts
    }
    __syncthreads();

    int lv = lperm[t];
    int cc2 = lcnt[lv];
    if (cc2 == 0) return;
    const int* row = lnbr + lv * 27;
    int n = base + lv;

    float acc[16];
    #pragma unroll
    for (int d = 0; d < 16; ++d) acc[d] = 0.f;
    int j = 0;
    while (j < cc2) {
        int m = cc2 - j; if (m > 4) m = 4;
        int e0 = 0, e1 = 0, e2 = 0, e3 = 0;
        float4 f0, f1, f2, f3;
        e0 = row[j];
        f0 = *(const float4*)(feats + (e0 >> 5) * 4);
        if (m > 1) { e1 = row[j + 1]; f1 = *(const float4*)(feats + (e1 >> 5) * 4); }
        if (m > 2) { e2 = row[j + 2]; f2 = *(const float4*)(feats + (e2 >> 5) * 4); }
        if (m > 3) { e3 = row[j + 3]; f3 = *(const float4*)(feats + (e3 >> 5) * 4); }
        conv0_entry(e0, f0, Wl, acc);
        if (m > 1) conv0_entry(e1, f1, Wl, acc);
        if (m > 2) conv0_entry(e2, f2, Wl, acc);
        if (m > 3) conv0_entry(e3, f3, Wl, acc);
        j += m;
    }
    float v[16];
    #pragma unroll
    for (int d = 0; d < 16; ++d) {
        float u = acc[d] * s[d] + b[d];
        v[d] = u > 0.f ? u : 0.f;
    }
    uint4 u0, u1;
    u0.x = packh2(v[0], v[1]);   u0.y = packh2(v[2], v[3]);
    u0.z = packh2(v[4], v[5]);   u0.w = packh2(v[6], v[7]);
    u1.x = packh2(v[8], v[9]);   u1.y = packh2(v[10], v[11]);
    u1.z = packh2(v[12], v[13]); u1.w = packh2(v[14], v[15]);
    ((uint4*)xh)[n * 2 + 0] = u0;
    ((uint4*)xh)[n * 2 + 1] = u1;
}

// ---------------- f16 dot2 block for one entry: 4 output channels d0..d0+3 ----------------
__device__ __forceinline__ void dot2_entry(int e, uint4 fa, uint4 fb, int d0,
                                           const uint32_t* __restrict__ wl, float acc[4]) {
    int k = e & 31;
    h2 f0 = toh2(fa.x), f1 = toh2(fa.y), f2 = toh2(fa.z), f3 = toh2(fa.w);
    h2 f4 = toh2(fb.x), f5 = toh2(fb.y), f6 = toh2(fb.z), f7 = toh2(fb.w);
    const uint32_t* wk = wl + k * WPITCH + d0 * 8;
    #pragma unroll
    for (int dd = 0; dd < 4; ++dd) {
        uint4 wa = *(const uint4*)(wk + dd * 8);
        uint4 wb = *(const uint4*)(wk + dd * 8 + 4);
        float a = acc[dd];
        a = __builtin_amdgcn_fdot2(f0, toh2(wa.x), a, false);
        a = __builtin_amdgcn_fdot2(f1, toh2(wa.y), a, false);
        a = __builtin_amdgcn_fdot2(f2, toh2(wa.z), a, false);
        a = __builtin_amdgcn_fdot2(f3, toh2(wa.w), a, false);
        a = __builtin_amdgcn_fdot2(f4, toh2(wb.x), a, false);
        a = __builtin_amdgcn_fdot2(f5, toh2(wb.y), a, false);
        a = __builtin_amdgcn_fdot2(f6, toh2(wb.z), a, false);
        a = __builtin_amdgcn_fdot2(f7, toh2(wb.w), a, false);
        acc[dd] = a;
    }
}

// ---------------- shared f16-dot2 conv core: 4 threads/voxel, batch-4 gathers -------------------
__device__ __forceinline__ void conv16_dot2(const uint32_t* __restrict__ fin,  // [N,8] f16 pairs
                                            const int* __restrict__ ent,
                                            int c, int n, int d0,
                                            const uint32_t* __restrict__ wl,
                                            float acc[4]) {
    #pragma unroll
    for (int d = 0; d < 4; ++d) acc[d] = 0.f;
    if (c <= 0) return;
    int j = 0;
    while (j < c) {
        int m = c - j; if (m > 4) m = 4;
        int e0 = 0, e1 = 0, e2 = 0, e3 = 0;
        uint4 fa0, fb0, fa1, fb1, fa2, fb2, fa3, fb3;
        // load entry words (independent), then all feature rows (independent) -> 4 gathers in flight
        e0 = ent[j * NVOX + n];
        if (m > 1) e1 = ent[(j + 1) * NVOX + n];
        if (m > 2) e2 = ent[(j + 2) * NVOX + n];
        if (m > 3) e3 = ent[(j + 3) * NVOX + n];
        { const uint4* fq = (const uint4*)(fin + (e0 >> 5) * 8); fa0 = fq[0]; fb0 = fq[1]; }
        if (m > 1) { const uint4* fq = (const uint4*)(fin + (e1 >> 5) * 8); fa1 = fq[0]; fb1 = fq[1]; }
        if (m > 2) { const uint4* fq = (const uint4*)(fin + (e2 >> 5) * 8); fa2 = fq[0]; fb2 = fq[1]; }
        if (m > 3) { const uint4* fq = (const uint4*)(fin + (e3 >> 5) * 8); fa3 = fq[0]; fb3 = fq[1]; }
        dot2_entry(e0, fa0, fb0, d0, wl, acc);
        if (m > 1) dot2_entry(e1, fa1, fb1, d0, wl, acc);
        if (m > 2) dot2_entry(e2, fa2, fb2, d0, wl, acc);
        if (m > 3) dot2_entry(e3, fa3, fb3, d0, wl, acc);
        j += m;
    }
}

// ---------------- per-block prologue: stage packed W + rank 64 voxels by cnt --------------------
__device__ __forceinline__ void stage_and_rank(const uint32_t* __restrict__ wp,
                                               const int* __restrict__ cnt,
                                               uint32_t* __restrict__ wl,
                                               int* __restrict__ lcnt, int* __restrict__ lperm,
                                               int base, int t) {
    for (int i = t; i < 3456; i += 256)
        wl[(i >> 7) * WPITCH + (i & 127)] = wp[i];   // coalesced (pre-packed by k0)
    if (t < VPB) {
        int n = base + t;
        lcnt[t] = (n < NVOX) ? cnt[n] : 0;
    }
    __syncthreads();
    if (t < VPB) {
        int me = lcnt[t];
        int r = 0;
        #pragma unroll 8
        for (int j2 = 0; j2 < VPB; ++j2) {
            int oj = lcnt[j2];
            r += (oj < me) || (oj == me && j2 < t);
        }
        lperm[r] = t;                 // ascending cnt -> waves get uniform trip counts
    }
    __syncthreads();
}

// ---------------- K2: conv1 (16->16) f16 dot2, relu(conv*s+b), h out f16 ------------------------
__global__ __launch_bounds__(256, 6) void k2_conv1(
    const uint32_t* __restrict__ xh,  // [N,8] f16 pairs
    const int* __restrict__ ent, const int* __restrict__ cnt,
    const uint32_t* __restrict__ wp,  // packed W1
    const float* __restrict__ s, const float* __restrict__ b,
    uint32_t* __restrict__ hh) {      // [N,8] f16 pairs
    __shared__ __align__(16) uint32_t wl[27 * WPITCH];  // 14256 B
    __shared__ int lcnt[VPB];
    __shared__ int lperm[VPB];
    int t = threadIdx.x;
    int base = blockIdx.x * VPB;
    stage_and_rank(wp, cnt, wl, lcnt, lperm, base, t);
    int g = t >> 2, cg = t & 3;
    int lv = lperm[g];
    int n = base + lv;
    bool valid = n < NVOX;
    int c = lcnt[lv];
    int d0 = cg * 4;
    float acc[4];
    conv16_dot2(xh, ent, valid ? c : 0, n, d0, wl, acc);
    if (!valid) return;
    float v[4];
    #pragma unroll
    for (int dd = 0; dd < 4; ++dd) {
        float u = acc[dd] * s[d0 + dd] + b[d0 + dd];
        v[dd] = u > 0.f ? u : 0.f;
    }
    uint2 o;
    o.x = packh2(v[0], v[1]);
    o.y = packh2(v[2], v[3]);
    *(uint2*)(hh + n * 8 + cg * 2) = o;
}

// ---------------- K3: conv2 f16 dot2 + residual + relu + final 16->3 linear ---------------------
__global__ __launch_bounds__(256, 6) void k3_conv2_final(
    const uint32_t* __restrict__ hh,  // [N,8]
    const int* __restrict__ ent, const int* __restrict__ cnt,
    const uint32_t* __restrict__ wp,  // packed W2
    const float* __restrict__ s, const float* __restrict__ b,
    const uint32_t* __restrict__ xh,  // residual [N,8]
    const float* __restrict__ Wlin,   // [16,3]
    const float* __restrict__ blin,   // [3]
    float* __restrict__ out) {        // [N,3] fp32
    __shared__ __align__(16) uint32_t wl[27 * WPITCH];
    __shared__ int lcnt[VPB];
    __shared__ int lperm[VPB];
    int t = threadIdx.x;
    int base = blockIdx.x * VPB;
    stage_and_rank(wp, cnt, wl, lcnt, lperm, base, t);
    int g = t >> 2, cg = t & 3;
    int lv = lperm[g];
    int n = base + lv;
    bool valid = n < NVOX;
    int c = lcnt[lv];
    int d0 = cg * 4;
    float acc[4];
    conv16_dot2(hh, ent, valid ? c : 0, n, d0, wl, acc);
    float o0 = 0.f, o1 = 0.f, o2 = 0.f;
    if (valid) {
        uint2 iv = *(const uint2*)(xh + n * 8 + cg * 2);
        h2 i0 = toh2(iv.x), i1 = toh2(iv.y);
        float idn[4] = {(float)i0.x, (float)i0.y, (float)i1.x, (float)i1.y};
        #pragma unroll
        for (int dd = 0; dd < 4; ++dd) {
            int d = d0 + dd;
            float u = acc[dd] * s[d] + b[d] + idn[dd];
            u = u > 0.f ? u : 0.f;
            o0 += u * Wlin[d * 3 + 0];
            o1 += u * Wlin[d * 3 + 1];
            o2 += u * Wlin[d * 3 + 2];
        }
    }
    // reduce across the 4 lanes of this voxel (lanes g*4 .. g*4+3)
    o0 += __shfl_xor(o0, 1); o0 += __shfl_xor(o0, 2);
    o1 += __shfl_xor(o1, 1); o1 += __shfl_xor(o1, 2);
    o2 += __shfl_xor(o2, 1); o2 += __shfl_xor(o2, 2);
    if (valid && cg == 0) {
        out[n * 3 + 0] = o0 + blin[0];
        out[n * 3 + 1] = o1 + blin[1];
        out[n * 3 + 2] = o2 + blin[2];
    }
}

extern "C" void kernel_launch(void* const* d_in, const int* in_sizes, int n_in,
                              void* d_out, int out_size, void* d_ws, size_t ws_size,
                              hipStream_t stream) {
    const float* feats = (const float*)d_in[0];
    const int*   nbr   = (const int*)d_in[1];
    const float* W0    = (const float*)d_in[2];
    const float* s0    = (const float*)d_in[3];
    const float* b0    = (const float*)d_in[4];
    const float* W1    = (const float*)d_in[5];
    const float* s1    = (const float*)d_in[6];
    const float* b1    = (const float*)d_in[7];
    const float* W2    = (const float*)d_in[8];
    const float* s2    = (const float*)d_in[9];
    const float* b2    = (const float*)d_in[10];
    const float* Wlin  = (const float*)d_in[11];
    const float* blin  = (const float*)d_in[12];
    float* out = (float*)d_out;

    char* ws = (char*)d_ws;
    int*      ent = (int*)(ws);                    // 27*N*4 = 21,600,000
    int*      cnt = (int*)(ws + 21600000);         //    800,000
    uint32_t* xh  = (uint32_t*)(ws + 22400000);    //  6,400,000
    uint32_t* hh  = (uint32_t*)(ws + 28800000);    //  6,400,000
    uint32_t* wp1 = (uint32_t*)(ws + 35200000);    //     13,824
    uint32_t* wp2 = (uint32_t*)(ws + 35213824);    //     13,824

    k0_pack<<<27, 256, 0, stream>>>(W1, W2, wp1, wp2);
    k1_compact_conv0<<<NT1, T1, 0, stream>>>(feats, nbr, W0, s0, b0, ent, cnt, xh);
    k2_conv1<<<NT2, 256, 0, stream>>>(xh, ent, cnt, wp1, s1, b1, hh);
    k3_conv2_final<<<NT2, 256, 0, stream>>>(hh, ent, cnt, wp2, s2, b2, xh, Wlin, blin, out);
}